// Round 8
// baseline (8310.128 us; speedup 1.0000x reference)
//
#include <hip/hip_runtime.h>

typedef _Float16 half8 __attribute__((ext_vector_type(8)));
typedef float f32x4 __attribute__((ext_vector_type(4)));

__device__ __forceinline__ float fast_sigmoid(float v) {
  return 1.0f / (1.0f + __expf(-v));
}
__device__ __forceinline__ float fast_tanh(float v) {
  return 2.0f / (1.0f + __expf(-2.0f * v)) - 1.0f;
}

__device__ __forceinline__ half8 cvt2(float4 a, float4 b) {
  half8 o;
  o[0] = (_Float16)a.x; o[1] = (_Float16)a.y; o[2] = (_Float16)a.z; o[3] = (_Float16)a.w;
  o[4] = (_Float16)b.x; o[5] = (_Float16)b.y; o[6] = (_Float16)b.z; o[7] = (_Float16)b.w;
  return o;
}

// ---------------------------------------------------------------------------
// prep: frag-ordered f16 copies of W1, W2 (head) and the fused [Wx; Wh]
// (384 x 1024) recurrence matrix Wc, wave-major so each rec wave's 192
// B-fragments are contiguous:  Wc[((m*12 + ks12)*64 + lane)*8 + s],
// m = wv*16 + q*4 + db -> ct = q*16 + wv + 4*db, col = ct*16 + (lane&15),
// k = ks12*32 + (lane>>4)*8 + s  (ks12<4 -> Wx row k; else Wh row k-128).
// ---------------------------------------------------------------------------
__global__ void __launch_bounds__(256) prep_kernel(
    const float* __restrict__ W1, const float* __restrict__ W2,
    const float* __restrict__ Wx, const float* __restrict__ Wh,
    _Float16* __restrict__ W1f, _Float16* __restrict__ W2f,
    _Float16* __restrict__ Wc)
{
  int idx = blockIdx.x * 256 + threadIdx.x;     // grid 2048 -> 0..524287
  if (idx < 131072) {
    int m  = idx >> 16;          // 0 -> W1, 1 -> W2
    int i2 = idx & 65535;
    int s = i2 & 7, lane = (i2 >> 3) & 63, ks = (i2 >> 9) & 7, ct = (i2 >> 12) & 15;
    int col = ct * 16 + (lane & 15);
    int k   = ks * 32 + (lane >> 4) * 8 + s;
    float v = (m == 0) ? W1[k * 256 + col] : W2[k * 256 + col];
    ((m == 0) ? W1f : W2f)[i2] = (_Float16)v;
  } else {
    int wc = idx - 131072;                      // [0, 393216)
    int s = wc & 7, lane = (wc >> 3) & 63;
    int rest = wc >> 9;                         // m*12 + ks12, m = 0..63
    int ks12 = rest % 12, m = rest / 12;
    int wv = m >> 4, q = (m >> 2) & 3, db = m & 3;
    int ct  = q * 16 + wv + 4 * db;
    int col = ct * 16 + (lane & 15);
    int kin = (lane >> 4) * 8 + s;
    float v = (ks12 < 4) ? Wx[(ks12 * 32 + kin) * 1024 + col]
                         : Wh[((ks12 - 4) * 32 + kin) * 1024 + col];
    Wc[wc] = (_Float16)v;
  }
}

// ---------------------------------------------------------------------------
// Recurrence v8 (ZERO EXCHANGE): 16 WGs x 16 batch rows; each WG computes all
// 1024 gate columns for its rows (K = 384 fused x|h). h(t) round-trips through
// LDS only; weights stream from L2 (768 KB, L2-resident). Wave w owns gate
// tiles ct ≡ w (mod 4) -> all 4 gates of each dim in one lane -> in-register
// LSTM epilogue, c-state in 16 VGPRs. One __syncthreads per step (4 waves).
// A-frags read directly from padded row-major LDS (2-way conflicts = free).
// ---------------------------------------------------------------------------
__global__ void __launch_bounds__(256, 1) lstm_rec_kernel(
    const float* __restrict__ x, const float* __restrict__ bias,
    const _Float16* __restrict__ Wc, _Float16* __restrict__ h_all)
{
  __shared__ __align__(16) _Float16 xs[2][16][136];   // x_t rows, f16 (pad->2-way)
  __shared__ __align__(16) _Float16 hs[2][16][264];   // h rows, f16 (pad->2-way)

  const int tid = threadIdx.x;
  const int lane = tid & 63, wv = tid >> 6;
  const int pc = lane & 15, lg = lane >> 4;
  const int b0 = blockIdx.x * 16;                // this WG's batch rows

  float bv[4][4];                                // bias[q][db] for this lane's dims
  #pragma unroll
  for (int q = 0; q < 4; ++q)
    #pragma unroll
    for (int db = 0; db < 4; ++db)
      bv[q][db] = bias[q * 256 + (wv + 4 * db) * 16 + pc];

  // per-wave B-frag base: frag (q,db,ks12) at Wc8[((q*4+db)*12 + ks12)*64]
  const half8* Wc8 = (const half8*)Wc + (size_t)wv * 12288 + lane;

  // init: hs[0] = 0 (h(-1)); xs[0] = x(0)
  for (int i = tid; i < 16 * 264; i += 256) ((_Float16*)hs[0])[i] = (_Float16)0.f;
  const int srow = tid >> 4, ssg = tid & 15;     // staging: 16 rows x 16 segs
  {
    const float4* xp = (const float4*)(x + ((size_t)(b0 + srow) * 512) * 128 + ssg * 8);
    *(half8*)&xs[0][srow][ssg * 8] = cvt2(xp[0], xp[1]);
  }
  __syncthreads();

  float cst[4][4];                               // c-state, persistent in VGPRs
  #pragma unroll
  for (int db = 0; db < 4; ++db)
    #pragma unroll
    for (int r = 0; r < 4; ++r) cst[db][r] = 0.f;

  for (int t = 0; t < 512; ++t) {
    const int cur = t & 1, nxt = cur ^ 1;

    // stage x(t+1) -> xs[nxt] (read this step by nobody)
    if (t < 511) {
      const float4* xp = (const float4*)(x + ((size_t)(b0 + srow) * 512 + (t + 1)) * 128 + ssg * 8);
      *(half8*)&xs[nxt][srow][ssg * 8] = cvt2(xp[0], xp[1]);
    }
    // store h(t-1) -> h_all, coalesced from hs[cur] (not written this step)
    if (t > 0) {
      const half8* hp = (const half8*)&hs[cur][srow][ssg * 16];
      half8 v0 = hp[0], v1 = hp[1];
      half8* gp = (half8*)(h_all + ((size_t)(t - 1) * 256 + b0 + srow) * 256 + ssg * 16);
      gp[0] = v0; gp[1] = v1;
    }

    // ---- MFMA: 12 k-slices x 16 gate tiles; B streamed from L2
    f32x4 acc[4][4];
    #pragma unroll
    for (int ks = 0; ks < 12; ++ks) {
      half8 av = (ks < 4)
          ? *(const half8*)&xs[cur][pc][ks * 32 + lg * 8]
          : *(const half8*)&hs[cur][pc][(ks - 4) * 32 + lg * 8];
      #pragma unroll
      for (int q = 0; q < 4; ++q)
        #pragma unroll
        for (int db = 0; db < 4; ++db) {
          f32x4 c = (ks == 0) ? (f32x4){0.f, 0.f, 0.f, 0.f} : acc[q][db];
          acc[q][db] = __builtin_amdgcn_mfma_f32_16x16x32_f16(
              av, Wc8[((q * 4 + db) * 12 + ks) * 64], c, 0, 0, 0);
        }
    }

    // ---- in-register LSTM epilogue; h(t) -> hs[nxt]
    #pragma unroll
    for (int db = 0; db < 4; ++db)
      #pragma unroll
      for (int r = 0; r < 4; ++r) {
        float iv = fast_sigmoid(acc[0][db][r] + bv[0][db]);
        float fv = fast_sigmoid(acc[1][db][r] + bv[1][db]);
        float gv = fast_tanh   (acc[2][db][r] + bv[2][db]);
        float ov = fast_sigmoid(acc[3][db][r] + bv[3][db]);
        float cv = fv * cst[db][r] + iv * gv;
        cst[db][r] = cv;
        hs[nxt][lg * 4 + r][(wv + 4 * db) * 16 + pc] = (_Float16)(ov * fast_tanh(cv));
      }
    __syncthreads();   // the ONLY barrier: nxt buffers ready, cur reads done
  }

  // store h(511) (sits in hs[512 & 1] = hs[0])
  {
    const half8* hp = (const half8*)&hs[0][srow][ssg * 16];
    half8 v0 = hp[0], v1 = hp[1];
    half8* gp = (half8*)(h_all + ((size_t)511 * 256 + b0 + srow) * 256 + ssg * 16);
    gp[0] = v0; gp[1] = v1;
  }
}

// ---------------------------------------------------------------------------
// Head: per WG 64 rows of [T*B, H]; fused GEMM1->tanh->GEMM2->tanh->dot(W3).
// (unchanged, validated r1-r7)
// ---------------------------------------------------------------------------
__device__ __forceinline__ void head_gemm(const _Float16* __restrict__ A,
                                          const _Float16* __restrict__ Wf,
                                          const float* __restrict__ bvec,
                                          _Float16* __restrict__ Yd,
                                          int lane, int w)
{
  const half8* Af = (const half8*)A + w * 512 + lane;
  for (int ct = 0; ct < 16; ++ct) {
    const half8* Bf = (const half8*)Wf + ct * 512 + lane;
    f32x4 acc = {0.f, 0.f, 0.f, 0.f};
    #pragma unroll
    for (int ks = 0; ks < 8; ++ks)
      acc = __builtin_amdgcn_mfma_f32_16x16x32_f16(Af[ks * 64], Bf[ks * 64], acc, 0, 0, 0);
    int col = ct * 16 + (lane & 15);
    float bb = bvec[col];
    int ks2 = col >> 5, kg2 = (col >> 3) & 3, s2 = col & 7;
    #pragma unroll
    for (int r = 0; r < 4; ++r) {
      int row = w * 16 + ((lane >> 4) << 2) + r;
      float v = fast_tanh(acc[r] + bb);
      Yd[(((w * 8 + ks2) * 64) + kg2 * 16 + (row & 15)) * 8 + s2] = (_Float16)v;
    }
  }
}

__global__ void __launch_bounds__(256) head_kernel(
    const _Float16* __restrict__ h_all,
    const _Float16* __restrict__ W1f, const _Float16* __restrict__ W2f,
    const float* __restrict__ b1, const float* __restrict__ b2,
    const float* __restrict__ W3, const float* __restrict__ b3,
    float* __restrict__ out)
{
  __shared__ __align__(16) _Float16 A_s[16384];   // 32 KB
  __shared__ __align__(16) _Float16 Y_s[16384];   // 32 KB
  const int tid = threadIdx.x;
  const size_t r0 = (size_t)blockIdx.x * 64;

  {
    int row = tid >> 2, seg = tid & 3;
    int rtl = row >> 4, lrow = row & 15;
    const half8* hp = (const half8*)(h_all + (r0 + row) * 256 + seg * 64);
    #pragma unroll
    for (int i = 0; i < 8; ++i) {
      int k0 = seg * 64 + i * 8;
      int ks = k0 >> 5, kg = (k0 >> 3) & 3;
      ((half8*)A_s)[(rtl * 8 + ks) * 64 + kg * 16 + lrow] = hp[i];
    }
  }
  __syncthreads();

  const int lane = tid & 63, w = tid >> 6;
  head_gemm(A_s, W1f, b1, Y_s, lane, w);   // y1 = tanh(h @ W1 + b1)
  __syncthreads();
  head_gemm(Y_s, W2f, b2, A_s, lane, w);   // y2 = tanh(y1 @ W2 + b2)
  __syncthreads();

  {
    int row = tid >> 2, part = tid & 3;
    int rtl = row >> 4, lrow = row & 15;
    float p = 0.f;
    #pragma unroll
    for (int kk = 0; kk < 8; ++kk) {
      int k0 = part * 64 + kk * 8;
      int ks = k0 >> 5, kg = (k0 >> 3) & 3;
      half8 y = ((const half8*)A_s)[(rtl * 8 + ks) * 64 + kg * 16 + lrow];
      #pragma unroll
      for (int i = 0; i < 8; ++i) p += (float)y[i] * W3[k0 + i];
    }
    p += __shfl_xor(p, 1);
    p += __shfl_xor(p, 2);
    if (part == 0) {
      size_t r = r0 + row;                 // r = t*256 + b
      int tt = (int)(r >> 8), bb = (int)(r & 255);
      out[(size_t)bb * 512 + tt] = p + b3[0];
    }
  }
}

// ---------------------------------------------------------------------------
extern "C" void kernel_launch(void* const* d_in, const int* in_sizes, int n_in,
                              void* d_out, int out_size, void* d_ws, size_t ws_size,
                              hipStream_t stream)
{
  const float* x  = (const float*)d_in[0];
  const float* Wx = (const float*)d_in[1];
  const float* Wh = (const float*)d_in[2];
  const float* b  = (const float*)d_in[3];
  const float* W1 = (const float*)d_in[4];
  const float* b1 = (const float*)d_in[5];
  const float* W2 = (const float*)d_in[6];
  const float* b2 = (const float*)d_in[7];
  const float* W3 = (const float*)d_in[8];
  const float* b3 = (const float*)d_in[9];
  float* out = (float*)d_out;

  char* ws = (char*)d_ws;
  _Float16* W1f   = (_Float16*)ws;                         // 128 KB
  _Float16* W2f   = (_Float16*)(ws + 131072);              // 128 KB
  _Float16* Wc    = (_Float16*)(ws + 262144);              // 768 KB fused frag weights
  _Float16* h_all = (_Float16*)(ws + 1048576);             // [512][256][256] f16 = 64 MB
  if (ws_size < (size_t)1048576 + 67108864) return;        // insufficient scratch

  hipLaunchKernelGGL(prep_kernel, dim3(2048), dim3(256), 0, stream,
                     W1, W2, Wx, Wh, W1f, W2f, Wc);
  hipLaunchKernelGGL(lstm_rec_kernel, dim3(16), dim3(256), 0, stream,
                     x, b, Wc, h_all);
  hipLaunchKernelGGL(head_kernel, dim3(2048), dim3(256), 0, stream,
                     h_all, W1f, W2f, b1, b2, W3, b3, out);
}

// Round 9
// 6954.232 us; speedup vs baseline: 1.1950x; 1.1950x over previous
//
#include <hip/hip_runtime.h>

typedef _Float16 half8 __attribute__((ext_vector_type(8)));
typedef float f32x4 __attribute__((ext_vector_type(4)));

__device__ __forceinline__ float fast_sigmoid(float v) {
  return 1.0f / (1.0f + __expf(-v));
}
__device__ __forceinline__ float fast_tanh(float v) {
  return 2.0f / (1.0f + __expf(-2.0f * v)) - 1.0f;
}

#define AL(p)    __hip_atomic_load((p), __ATOMIC_RELAXED, __HIP_MEMORY_SCOPE_AGENT)
#define AS(p, x) __hip_atomic_store((p), (x), __ATOMIC_RELAXED, __HIP_MEMORY_SCOPE_AGENT)
#define TAGMSK 0xFFFF0000FFFF0000ull

__device__ __forceinline__ half8 cvt2(float4 a, float4 b) {
  half8 o;
  o[0] = (_Float16)a.x; o[1] = (_Float16)a.y; o[2] = (_Float16)a.z; o[3] = (_Float16)a.w;
  o[4] = (_Float16)b.x; o[5] = (_Float16)b.y; o[6] = (_Float16)b.z; o[7] = (_Float16)b.w;
  return o;
}

// ---------------------------------------------------------------------------
// prep: frag-ordered f16 copies of W1, W2 for the head GEMMs.
// ---------------------------------------------------------------------------
__global__ void __launch_bounds__(256) prep_kernel(
    const float* __restrict__ W1, const float* __restrict__ W2,
    _Float16* __restrict__ W1f, _Float16* __restrict__ W2f)
{
  int idx = blockIdx.x * 256 + threadIdx.x;   // grid 512 -> 0..131071
  int m  = idx >> 16;          // 0 -> W1, 1 -> W2
  int i2 = idx & 65535;
  int s = i2 & 7, lane = (i2 >> 3) & 63, ks = (i2 >> 9) & 7, ct = (i2 >> 12) & 15;
  int col = ct * 16 + (lane & 15);
  int k   = ks * 32 + (lane >> 4) * 8 + s;
  float v = (m == 0) ? W1[k * 256 + col] : W2[k * 256 + col];
  ((m == 0) ? W1f : W2f)[i2] = (_Float16)v;
}

// ---------------------------------------------------------------------------
// Recurrence v9: C=2 round-robin chains per WG. 32 WGs = 4 sets x 8 col-WGs;
// set p serves groups g0=2p, g1=2p+1 (32 batch rows each) with ONE shared
// 96 KB LDS weight slice (K=384 fused x|h, 128 gate-cols: all 4 gates of
// h-dims j*32..+31). Per phase: one (group, timestep). Exchange = tagged u32
// (tag=t+1 | f16h) in ping-pong hx, agent-scope u64 loads (r6-validated
// mechanics); a chain's data is stored 2 phases before consumption and
// prefetched 1 phase ahead -> tags hit first try, exchange off critical path.
// NO flags, NO fences, NO drain barriers. A-frags in registers; in-register
// LSTM epilogue (r4-validated); one __syncthreads per phase (h_s ping-pong).
// ---------------------------------------------------------------------------
#define PHASE(G, HS, HV, HVO, XL, CST, ISS_EN, ISS_SLOT, ISS_G)                \
  {                                                                            \
    const int b0 = (G) * 32;                                                   \
    /* convert this phase's x (loaded one round ago) */                        \
    half8 XF0 = cvt2(XL[0], XL[1]), XF1 = cvt2(XL[2], XL[3]);                  \
    half8 XF2 = cvt2(XL[4], XL[5]), XF3 = cvt2(XL[6], XL[7]);                  \
    /* verify tags of prefetched h(t-1); rare reload on mismatch */            \
    half8 HF[8];                                                               \
    if (t > 0) {                                                               \
      const unsigned long long want =                                          \
          ((unsigned long long)(unsigned)t << 16) |                            \
          ((unsigned long long)(unsigned)t << 48);                             \
      unsigned long long diff = 0;                                             \
      _Pragma("unroll") for (int i = 0; i < 32; ++i)                           \
        diff |= (HV[i] & TAGMSK) ^ want;                                       \
      if (__builtin_expect(diff != 0, 0)) {                                    \
        const unsigned long long* hp = (const unsigned long long*)hx_st +      \
            ((size_t)((((t - 1) & 1) * 8 + (G)) * 32 + arow)) * 128 + lg * 4;  \
        int iters = 0;                                                         \
        do {                                                                   \
          diff = 0;                                                            \
          _Pragma("unroll") for (int ks = 0; ks < 8; ++ks)                     \
            _Pragma("unroll") for (int i = 0; i < 4; ++i) {                    \
              HV[ks * 4 + i] = AL(hp + ks * 16 + i);                           \
              diff |= (HV[ks * 4 + i] & TAGMSK) ^ want;                        \
            }                                                                  \
          if (diff) __builtin_amdgcn_s_sleep(2);                               \
        } while (diff != 0 && ++iters < (1 << 15));  /* valve, not hang */     \
      }                                                                        \
      _Pragma("unroll") for (int ks = 0; ks < 8; ++ks) {                       \
        union { unsigned u[4]; half8 v; } pk;                                  \
        _Pragma("unroll") for (int i = 0; i < 4; ++i) {                        \
          unsigned long long vv = HV[ks * 4 + i];                              \
          pk.u[i] = ((unsigned)vv & 0xFFFFu) | ((unsigned)(vv >> 32) << 16);   \
        }                                                                      \
        HF[ks] = pk.v;                                                         \
      }                                                                        \
    } else {                                                                   \
      _Pragma("unroll") for (int ks = 0; ks < 8; ++ks) HF[ks] = (half8){};     \
    }                                                                          \
    /* HV regs now free: issue NEXT phase's tagged prefetch */                 \
    if (ISS_EN) {                                                              \
      const unsigned long long* hp = (const unsigned long long*)hx_st +        \
          ((size_t)(((ISS_SLOT) * 8 + (ISS_G)) * 32 + arow)) * 128 + lg * 4;   \
      _Pragma("unroll") for (int ks = 0; ks < 8; ++ks)                         \
        _Pragma("unroll") for (int i = 0; i < 4; ++i)                          \
          HVO[ks * 4 + i] = AL(hp + ks * 16 + i);                              \
    }                                                                          \
    /* issue this chain's x(t+1) load (consumed next round) */                 \
    if (t < 511) {                                                             \
      const float4* xp = (const float4*)x +                                    \
          ((size_t)(b0 + arow) * 512 + t + 1) * 32 + lg * 2;                   \
      _Pragma("unroll") for (int ks = 0; ks < 4; ++ks) {                       \
        XL[ks * 2 + 0] = xp[ks * 8 + 0];                                       \
        XL[ks * 2 + 1] = xp[ks * 8 + 1];                                       \
      }                                                                        \
    }                                                                          \
    /* MFMA: 12 k-slices x 4 gate tiles (ct = 2q+e); A regs, B LDS */          \
    f32x4 a0 = {0.f, 0.f, 0.f, 0.f}, a1 = a0, a2 = a0, a3 = a0;                \
    _Pragma("unroll") for (int ks = 0; ks < 12; ++ks) {                        \
      half8 av;                                                                \
      if (ks == 0) av = XF0; else if (ks == 1) av = XF1;                       \
      else if (ks == 2) av = XF2; else if (ks == 3) av = XF3;                  \
      else av = HF[ks - 4];                                                    \
      a0 = __builtin_amdgcn_mfma_f32_16x16x32_f16(                             \
          av, Wp8[((0 + e) * 12 + ks) * 64 + lane], a0, 0, 0, 0);              \
      a1 = __builtin_amdgcn_mfma_f32_16x16x32_f16(                             \
          av, Wp8[((2 + e) * 12 + ks) * 64 + lane], a1, 0, 0, 0);              \
      a2 = __builtin_amdgcn_mfma_f32_16x16x32_f16(                             \
          av, Wp8[((4 + e) * 12 + ks) * 64 + lane], a2, 0, 0, 0);              \
      a3 = __builtin_amdgcn_mfma_f32_16x16x32_f16(                             \
          av, Wp8[((6 + e) * 12 + ks) * 64 + lane], a3, 0, 0, 0);              \
    }                                                                          \
    /* in-register LSTM epilogue; tagged hx stores (self-validating) */        \
    _Pragma("unroll") for (int r = 0; r < 4; ++r) {                            \
      float iv = fast_sigmoid(a0[r] + bv0);                                    \
      float fv = fast_sigmoid(a1[r] + bv1);                                    \
      float gv = fast_tanh   (a2[r] + bv2);                                    \
      float ov = fast_sigmoid(a3[r] + bv3);                                    \
      float cv = fv * CST[r] + iv * gv;                                        \
      CST[r] = cv;                                                             \
      float hvl = ov * fast_tanh(cv);                                          \
      _Float16 hf16 = (_Float16)hvl;                                           \
      unsigned short hb16; __builtin_memcpy(&hb16, &hf16, 2);                  \
      h_s[HS][prow + r][e * 16 + pc] = hf16;                                   \
      AS(hx_st + ((size_t)(((t & 1) * 8 + (G)) * 32 + prow + r)) * 256         \
               + j * 32 + e * 16 + pc,                                         \
         ((unsigned)(t + 1) << 16) | (unsigned)hb16);                          \
    }                                                                          \
    __syncthreads();   /* h_s[HS] complete; ping-pong protects reuse */        \
    /* coalesced h_all store (plain; head runs after kernel boundary) */       \
    {                                                                          \
      unsigned long long hv8;                                                  \
      __builtin_memcpy(&hv8, &h_s[HS][tid >> 3][(tid & 7) * 4], 8);            \
      *(unsigned long long*)(h_all +                                           \
          ((size_t)t * 256 + b0 + (tid >> 3)) * 256 + j * 32 + (tid & 7) * 4)  \
          = hv8;                                                               \
    }                                                                          \
  }

__global__ void __launch_bounds__(256, 1) lstm_rec_kernel(
    const float* __restrict__ x, const float* __restrict__ Wx,
    const float* __restrict__ Wh, const float* __restrict__ bias,
    unsigned* __restrict__ hx_st, _Float16* __restrict__ h_all)
{
  __shared__ __align__(16) _Float16 Wt[8 * 12 * 64 * 8];   // 96 KB [ct][ks][lane][8]
  __shared__ __align__(8)  _Float16 h_s[2][32][36];        // 4.6 KB ping-pong

  const int tid = threadIdx.x;
  const int p = blockIdx.x & 3;     // WG-set -> groups 2p, 2p+1
  const int j = blockIdx.x >> 2;    // col-WG 0..7: h-dims j*32..j*32+31
  const int g0 = 2 * p, g1 = 2 * p + 1;

  // ---- one-time: weight slice 384 x 128 as f16 B-frags (ct = 2q + (d>=16))
  for (int idx = tid; idx < 384 * 128; idx += 256) {
    int k = idx >> 7, c = idx & 127;          // c = q*32 + d
    int q = c >> 5, d = c & 31;
    int gc = q * 256 + j * 32 + d;
    float v = (k < 128) ? Wx[k * 1024 + gc] : Wh[(k - 128) * 1024 + gc];
    int ct = 2 * q + (d >> 4), lcol = d & 15;
    int ks = k >> 5, kg = (k >> 3) & 3, s = k & 7;
    Wt[(((ct * 12 + ks) * 64) + kg * 16 + lcol) * 8 + s] = (_Float16)v;
  }

  const int lane = tid & 63, wid = tid >> 6;
  const int rt = wid & 1, e = wid >> 1;
  const int pc = lane & 15, lg = lane >> 4;
  const int arow = rt * 16 + pc;               // A-frag row this lane loads
  const int prow = rt * 16 + lg * 4;           // C/D row base this lane owns

  const float bv0 = bias[0 * 256 + j * 32 + e * 16 + pc];
  const float bv1 = bias[1 * 256 + j * 32 + e * 16 + pc];
  const float bv2 = bias[2 * 256 + j * 32 + e * 16 + pc];
  const float bv3 = bias[3 * 256 + j * 32 + e * 16 + pc];

  const half8* Wp8 = (const half8*)Wt;

  // preload x(g,0) for both chains
  float4 XLA[8], XLB[8];
  {
    const float4* xa = (const float4*)x + ((size_t)(g0 * 32 + arow) * 512) * 32 + lg * 2;
    const float4* xb = (const float4*)x + ((size_t)(g1 * 32 + arow) * 512) * 32 + lg * 2;
    #pragma unroll
    for (int ks = 0; ks < 4; ++ks) {
      XLA[ks * 2 + 0] = xa[ks * 8 + 0]; XLA[ks * 2 + 1] = xa[ks * 8 + 1];
      XLB[ks * 2 + 0] = xb[ks * 8 + 0]; XLB[ks * 2 + 1] = xb[ks * 8 + 1];
    }
  }

  unsigned long long HVA[32], HVB[32];
  #pragma unroll
  for (int i = 0; i < 32; ++i) { HVA[i] = 0ull; HVB[i] = 0ull; }
  float cstA[4] = {0.f, 0.f, 0.f, 0.f}, cstB[4] = {0.f, 0.f, 0.f, 0.f};

  __syncthreads();   // Wt ready

  for (int t = 0; t < 512; ++t) {
    // phase A: group g0 step t; prefetch HVB for B(t) (want tag t, stored end
    // of B(t-1), ~1 phase ago)
    PHASE(g0, 0, HVA, HVB, XLA, cstA, (t > 0), ((t - 1) & 1), g1)
    // phase B: group g1 step t; prefetch HVA for A(t+1) (want tag t+1, stored
    // end of this round's phase A, ~1 phase ago)
    PHASE(g1, 1, HVB, HVA, XLB, cstB, (t < 511), (t & 1), g0)
  }
}

// ---------------------------------------------------------------------------
// Head: per WG 64 rows of [T*B, H]; fused GEMM1->tanh->GEMM2->tanh->dot(W3).
// (unchanged, validated r1-r8)
// ---------------------------------------------------------------------------
__device__ __forceinline__ void head_gemm(const _Float16* __restrict__ A,
                                          const _Float16* __restrict__ Wf,
                                          const float* __restrict__ bvec,
                                          _Float16* __restrict__ Yd,
                                          int lane, int w)
{
  const half8* Af = (const half8*)A + w * 512 + lane;
  for (int ct = 0; ct < 16; ++ct) {
    const half8* Bf = (const half8*)Wf + ct * 512 + lane;
    f32x4 acc = {0.f, 0.f, 0.f, 0.f};
    #pragma unroll
    for (int ks = 0; ks < 8; ++ks)
      acc = __builtin_amdgcn_mfma_f32_16x16x32_f16(Af[ks * 64], Bf[ks * 64], acc, 0, 0, 0);
    int col = ct * 16 + (lane & 15);
    float bb = bvec[col];
    int ks2 = col >> 5, kg2 = (col >> 3) & 3, s2 = col & 7;
    #pragma unroll
    for (int r = 0; r < 4; ++r) {
      int row = w * 16 + ((lane >> 4) << 2) + r;
      float v = fast_tanh(acc[r] + bb);
      Yd[(((w * 8 + ks2) * 64) + kg2 * 16 + (row & 15)) * 8 + s2] = (_Float16)v;
    }
  }
}

__global__ void __launch_bounds__(256) head_kernel(
    const _Float16* __restrict__ h_all,
    const _Float16* __restrict__ W1f, const _Float16* __restrict__ W2f,
    const float* __restrict__ b1, const float* __restrict__ b2,
    const float* __restrict__ W3, const float* __restrict__ b3,
    float* __restrict__ out)
{
  __shared__ __align__(16) _Float16 A_s[16384];   // 32 KB
  __shared__ __align__(16) _Float16 Y_s[16384];   // 32 KB
  const int tid = threadIdx.x;
  const size_t r0 = (size_t)blockIdx.x * 64;

  {
    int row = tid >> 2, seg = tid & 3;
    int rtl = row >> 4, lrow = row & 15;
    const half8* hp = (const half8*)(h_all + (r0 + row) * 256 + seg * 64);
    #pragma unroll
    for (int i = 0; i < 8; ++i) {
      int k0 = seg * 64 + i * 8;
      int ks = k0 >> 5, kg = (k0 >> 3) & 3;
      ((half8*)A_s)[(rtl * 8 + ks) * 64 + kg * 16 + lrow] = hp[i];
    }
  }
  __syncthreads();

  const int lane = tid & 63, w = tid >> 6;
  head_gemm(A_s, W1f, b1, Y_s, lane, w);   // y1 = tanh(h @ W1 + b1)
  __syncthreads();
  head_gemm(Y_s, W2f, b2, A_s, lane, w);   // y2 = tanh(y1 @ W2 + b2)
  __syncthreads();

  {
    int row = tid >> 2, part = tid & 3;
    int rtl = row >> 4, lrow = row & 15;
    float p = 0.f;
    #pragma unroll
    for (int kk = 0; kk < 8; ++kk) {
      int k0 = part * 64 + kk * 8;
      int ks = k0 >> 5, kg = (k0 >> 3) & 3;
      half8 y = ((const half8*)A_s)[(rtl * 8 + ks) * 64 + kg * 16 + lrow];
      #pragma unroll
      for (int i = 0; i < 8; ++i) p += (float)y[i] * W3[k0 + i];
    }
    p += __shfl_xor(p, 1);
    p += __shfl_xor(p, 2);
    if (part == 0) {
      size_t r = r0 + row;                 // r = t*256 + b
      int tt = (int)(r >> 8), bb = (int)(r & 255);
      out[(size_t)bb * 512 + tt] = p + b3[0];
    }
  }
}

// ---------------------------------------------------------------------------
extern "C" void kernel_launch(void* const* d_in, const int* in_sizes, int n_in,
                              void* d_out, int out_size, void* d_ws, size_t ws_size,
                              hipStream_t stream)
{
  const float* x  = (const float*)d_in[0];
  const float* Wx = (const float*)d_in[1];
  const float* Wh = (const float*)d_in[2];
  const float* b  = (const float*)d_in[3];
  const float* W1 = (const float*)d_in[4];
  const float* b1 = (const float*)d_in[5];
  const float* W2 = (const float*)d_in[6];
  const float* b2 = (const float*)d_in[7];
  const float* W3 = (const float*)d_in[8];
  const float* b3 = (const float*)d_in[9];
  float* out = (float*)d_out;

  char* ws = (char*)d_ws;
  unsigned*  hx    = (unsigned*)ws;                        // tagged ping-pong h: 512 KB
  _Float16*  W1f   = (_Float16*)(ws + 524288);             // 128 KB
  _Float16*  W2f   = (_Float16*)(ws + 655360);             // 128 KB
  _Float16*  h_all = (_Float16*)(ws + 786432);             // [512][256][256] f16 = 64 MB
  if (ws_size < (size_t)786432 + 67108864) return;         // insufficient scratch

  hipMemsetAsync(hx, 0, 524288, stream);   // clear tags every replay
  hipLaunchKernelGGL(prep_kernel, dim3(512), dim3(256), 0, stream,
                     W1, W2, W1f, W2f);
  hipLaunchKernelGGL(lstm_rec_kernel, dim3(32), dim3(256), 0, stream,
                     x, Wx, Wh, b, hx, h_all);
  hipLaunchKernelGGL(head_kernel, dim3(2048), dim3(256), 0, stream,
                     h_all, W1f, W2f, b1, b2, W3, b3, out);
}

// Round 10
// 4002.911 us; speedup vs baseline: 2.0760x; 1.7373x over previous
//
#include <hip/hip_runtime.h>

typedef _Float16 half8 __attribute__((ext_vector_type(8)));
typedef float f32x4 __attribute__((ext_vector_type(4)));

__device__ __forceinline__ float fast_sigmoid(float v) {
  return 1.0f / (1.0f + __expf(-v));
}
__device__ __forceinline__ float fast_tanh(float v) {
  return 2.0f / (1.0f + __expf(-2.0f * v)) - 1.0f;
}

#define AL(p)    __hip_atomic_load((p), __ATOMIC_RELAXED, __HIP_MEMORY_SCOPE_AGENT)
#define AS(p, x) __hip_atomic_store((p), (x), __ATOMIC_RELAXED, __HIP_MEMORY_SCOPE_AGENT)
// LDS frag-index swizzle (r4-validated): spreads staging writes across banks.
#define SWZ(i) ((i) ^ (((i) >> 6) & 7))

__device__ __forceinline__ half8 cvt2(float4 a, float4 b) {
  half8 o;
  o[0] = (_Float16)a.x; o[1] = (_Float16)a.y; o[2] = (_Float16)a.z; o[3] = (_Float16)a.w;
  o[4] = (_Float16)b.x; o[5] = (_Float16)b.y; o[6] = (_Float16)b.z; o[7] = (_Float16)b.w;
  return o;
}

// ---------------------------------------------------------------------------
// prep: frag-ordered f16 copies of W1, W2 for the head GEMMs.
// ---------------------------------------------------------------------------
__global__ void __launch_bounds__(256) prep_kernel(
    const float* __restrict__ W1, const float* __restrict__ W2,
    _Float16* __restrict__ W1f, _Float16* __restrict__ W2f)
{
  int idx = blockIdx.x * 256 + threadIdx.x;   // grid 512 -> 0..131071
  int m  = idx >> 16;          // 0 -> W1, 1 -> W2
  int i2 = idx & 65535;
  int s = i2 & 7, lane = (i2 >> 3) & 63, ks = (i2 >> 9) & 7, ct = (i2 >> 12) & 15;
  int col = ct * 16 + (lane & 15);
  int k   = ks * 32 + (lane >> 4) * 8 + s;
  float v = (m == 0) ? W1[k * 256 + col] : W2[k * 256 + col];
  ((m == 0) ? W1f : W2f)[i2] = (_Float16)v;
}

// ---------------------------------------------------------------------------
// Recurrence v10 = r3 protocol + intra-WG surgery. 8 groups (32 rows) x 8
// col-WGs (h-dims j*32..+31, all 4 gates). Wave (rt,e): rows rt*16..,
// dims e*16..; gate tiles ct = 2q+e -> in-register LSTM epilogue, c in VGPRs.
// h-part B-frags pinned in VGPRs (in-loop asm pin). x reg-resident. Per-wave
// h stores (own 16x16 subtile via 2KB LDS transpose) + per-wave flags after
// own vmcnt drain -> ONE __syncthreads per step. Exchange = r3's validated
// flags + agent atomics; consumers poll 32 flags (one 128B line per group).
// ---------------------------------------------------------------------------
__global__ void __launch_bounds__(256, 1) lstm_rec_kernel(
    const float* __restrict__ x, const float* __restrict__ Wx,
    const float* __restrict__ Wh, const float* __restrict__ bias,
    _Float16* __restrict__ h_all, unsigned* __restrict__ flags)
{
  __shared__ __align__(16) _Float16 Wt[8 * 12 * 64 * 8];  // 96 KB [ct][12ks][64][8]
  __shared__ __align__(16) _Float16 At[2 * 8 * 64 * 8];   // 16 KB h A-frags
  __shared__ __align__(8)  _Float16 h_s[4][16][16];       // 2 KB per-wave transpose

  const int tid = threadIdx.x;
  const int g  = blockIdx.x & 7;    // group: rows g*32.. (consecutive blk -> one XCD)
  const int j  = blockIdx.x >> 3;   // col-WG: h-dims j*32..j*32+31
  const int b0 = g * 32;

  // ---- one-time: weight slice 384 x 128 as f16 B-frags (ct = 2q + (d>=16))
  for (int idx = tid; idx < 384 * 128; idx += 256) {
    int k = idx >> 7, c = idx & 127;          // c = q*32 + d
    int q = c >> 5, d = c & 31;
    int gc = q * 256 + j * 32 + d;
    float v = (k < 128) ? Wx[k * 1024 + gc] : Wh[(k - 128) * 1024 + gc];
    int ct = 2 * q + (d >> 4), lcol = d & 15;
    int ks = k >> 5, kg = (k >> 3) & 3, s = k & 7;
    Wt[(((ct * 12 + ks) * 64) + kg * 16 + lcol) * 8 + s] = (_Float16)v;
  }

  const int lane = tid & 63, wid = tid >> 6;
  const int rt = wid & 1, e = wid >> 1;
  const int pc = lane & 15, lg = lane >> 4;
  const int prow = rt * 16 + lg * 4;           // C/D row base this lane owns
  const int arow = rt * 16 + pc;               // A-frag row this lane loads

  const float bv0 = bias[0 * 256 + j * 32 + e * 16 + pc];
  const float bv1 = bias[1 * 256 + j * 32 + e * 16 + pc];
  const float bv2 = bias[2 * 256 + j * 32 + e * 16 + pc];
  const float bv3 = bias[3 * 256 + j * 32 + e * 16 + pc];

  const int srow = tid >> 3, sseg = tid & 7;   // h staging: 32 rows x 8 segs
  const int s_rt = srow >> 4, s_lrow = srow & 15;
  const int hbL = (s_rt * 8 + sseg) * 64 + s_lrow;   // half8 index in At

  half8* At8 = (half8*)At;
  const half8* Wp8 = (const half8*)Wt;
  const float4* xl4 = (const float4*)x + (size_t)(b0 + arow) * 16384 + lg * 2;

  __syncthreads();   // Wt ready

  // ---- hoist h-part B-frags (q=0..3, ks=4..11) into 128 VGPRs
  half8 Bh[32];
  #pragma unroll
  for (int q = 0; q < 4; ++q)
    #pragma unroll
    for (int ks = 0; ks < 8; ++ks)
      Bh[q * 8 + ks] = Wp8[((2 * q + e) * 12 + 4 + ks) * 64 + lane];

  // ---- pre-loop: XL = x(0); ax = x-part(0); XL <- x(1)
  float4 XL[8];
  #pragma unroll
  for (int ks = 0; ks < 4; ++ks) {
    XL[2 * ks]     = xl4[ks * 8];
    XL[2 * ks + 1] = xl4[ks * 8 + 1];
  }
  f32x4 ax0 = {0.f, 0.f, 0.f, 0.f}, ax1 = ax0, ax2 = ax0, ax3 = ax0;
  {
    half8 XF0 = cvt2(XL[0], XL[1]), XF1 = cvt2(XL[2], XL[3]);
    half8 XF2 = cvt2(XL[4], XL[5]), XF3 = cvt2(XL[6], XL[7]);
    #pragma unroll
    for (int ks = 0; ks < 4; ++ks) {
      half8 av = (ks == 0) ? XF0 : (ks == 1) ? XF1 : (ks == 2) ? XF2 : XF3;
      ax0 = __builtin_amdgcn_mfma_f32_16x16x32_f16(av, Wp8[((0 + e) * 12 + ks) * 64 + lane], ax0, 0, 0, 0);
      ax1 = __builtin_amdgcn_mfma_f32_16x16x32_f16(av, Wp8[((2 + e) * 12 + ks) * 64 + lane], ax1, 0, 0, 0);
      ax2 = __builtin_amdgcn_mfma_f32_16x16x32_f16(av, Wp8[((4 + e) * 12 + ks) * 64 + lane], ax2, 0, 0, 0);
      ax3 = __builtin_amdgcn_mfma_f32_16x16x32_f16(av, Wp8[((6 + e) * 12 + ks) * 64 + lane], ax3, 0, 0, 0);
    }
    #pragma unroll
    for (int ks = 0; ks < 4; ++ks) {
      XL[2 * ks]     = xl4[32 + ks * 8];
      XL[2 * ks + 1] = xl4[32 + ks * 8 + 1];
    }
  }

  float cst[4] = {0.f, 0.f, 0.f, 0.f};

  for (int t = 0; t < 512; ++t) {
    // ---- force B-frags live across the backedge (defeats LDS remat)
    #pragma unroll
    for (int i = 0; i < 32; ++i) asm volatile("" : "+v"(Bh[i]));

    // ---- poll producers (32 per-wave flags, one line) + stage h(t-1)
    if (t > 0) {
      int iters = 0;
      while (true) {
        unsigned v = (lane < 32) ? AL(&flags[g * 32 + lane]) : (unsigned)t;
        if (__ballot(v >= (unsigned)t) == ~0ull) break;
        if (++iters > (1 << 17)) break;   // valve: garbage instead of hang
        __builtin_amdgcn_s_sleep(1);
      }
      const unsigned long long* hp = (const unsigned long long*)h_all +
          ((size_t)(t - 1) * 256 + b0 + srow) * 64 + sseg * 8;
      union { unsigned long long u[2]; half8 v; } c0, c1, c2, c3;
      c0.u[0] = AL(hp + 0); c0.u[1] = AL(hp + 1);
      c1.u[0] = AL(hp + 2); c1.u[1] = AL(hp + 3);
      c2.u[0] = AL(hp + 4); c2.u[1] = AL(hp + 5);
      c3.u[0] = AL(hp + 6); c3.u[1] = AL(hp + 7);
      At8[SWZ(hbL)]      = c0.v; At8[SWZ(hbL + 16)] = c1.v;
      At8[SWZ(hbL + 32)] = c2.v; At8[SWZ(hbL + 48)] = c3.v;
    } else {
      half8 zz = {};
      At8[SWZ(hbL)]      = zz; At8[SWZ(hbL + 16)] = zz;
      At8[SWZ(hbL + 32)] = zz; At8[SWZ(hbL + 48)] = zz;
    }
    __syncthreads();   // B1: h frags ready (the ONLY barrier per step)

    // ---- h-part MFMA on top of precomputed x-part; B from pinned VGPRs
    f32x4 a0 = ax0, a1 = ax1, a2 = ax2, a3 = ax3;
    #pragma unroll
    for (int ks = 0; ks < 8; ++ks) {
      half8 av = At8[SWZ((rt * 8 + ks) * 64 + lane)];
      a0 = __builtin_amdgcn_mfma_f32_16x16x32_f16(av, Bh[0 * 8 + ks], a0, 0, 0, 0);
      a1 = __builtin_amdgcn_mfma_f32_16x16x32_f16(av, Bh[1 * 8 + ks], a1, 0, 0, 0);
      a2 = __builtin_amdgcn_mfma_f32_16x16x32_f16(av, Bh[2 * 8 + ks], a2, 0, 0, 0);
      a3 = __builtin_amdgcn_mfma_f32_16x16x32_f16(av, Bh[3 * 8 + ks], a3, 0, 0, 0);
    }

    // ---- in-register LSTM epilogue; h -> per-wave LDS transpose patch
    #pragma unroll
    for (int r = 0; r < 4; ++r) {
      float iv = fast_sigmoid(a0[r] + bv0);
      float fv = fast_sigmoid(a1[r] + bv1);
      float gv = fast_tanh   (a2[r] + bv2);
      float ov = fast_sigmoid(a3[r] + bv3);
      float cv = fv * cst[r] + iv * gv;
      cst[r] = cv;
      h_s[wid][lg * 4 + r][pc] = (_Float16)(ov * fast_tanh(cv));
    }

    // ---- per-wave coalesced u64 store of OWN subtile; own drain; own flag
    {
      unsigned long long hv8;
      __builtin_memcpy(&hv8, &h_s[wid][lane >> 2][(lane & 3) * 4], 8);
      unsigned long long* gp = (unsigned long long*)h_all +
          ((size_t)t * 256 + b0 + rt * 16 + (lane >> 2)) * 64 +
          j * 8 + e * 4 + (lane & 3);
      AS(gp, hv8);
    }
    asm volatile("s_waitcnt vmcnt(0)" ::: "memory");
    if (lane == 0)
      __hip_atomic_store(&flags[g * 32 + j * 4 + wid], (unsigned)(t + 1),
                         __ATOMIC_RELEASE, __HIP_MEMORY_SCOPE_AGENT);

    // ---- tail (overlap window): x-part MFMA for t+1; prefetch x(t+2)
    if (t < 511) {
      half8 XF0 = cvt2(XL[0], XL[1]), XF1 = cvt2(XL[2], XL[3]);
      half8 XF2 = cvt2(XL[4], XL[5]), XF3 = cvt2(XL[6], XL[7]);
      ax0 = (f32x4){0.f, 0.f, 0.f, 0.f}; ax1 = ax0; ax2 = ax0; ax3 = ax0;
      #pragma unroll
      for (int ks = 0; ks < 4; ++ks) {
        half8 av = (ks == 0) ? XF0 : (ks == 1) ? XF1 : (ks == 2) ? XF2 : XF3;
        ax0 = __builtin_amdgcn_mfma_f32_16x16x32_f16(av, Wp8[((0 + e) * 12 + ks) * 64 + lane], ax0, 0, 0, 0);
        ax1 = __builtin_amdgcn_mfma_f32_16x16x32_f16(av, Wp8[((2 + e) * 12 + ks) * 64 + lane], ax1, 0, 0, 0);
        ax2 = __builtin_amdgcn_mfma_f32_16x16x32_f16(av, Wp8[((4 + e) * 12 + ks) * 64 + lane], ax2, 0, 0, 0);
        ax3 = __builtin_amdgcn_mfma_f32_16x16x32_f16(av, Wp8[((6 + e) * 12 + ks) * 64 + lane], ax3, 0, 0, 0);
      }
      int tn = (t + 2 < 512) ? (t + 2) : 511;
      #pragma unroll
      for (int ks = 0; ks < 4; ++ks) {
        XL[2 * ks]     = xl4[(size_t)tn * 32 + ks * 8];
        XL[2 * ks + 1] = xl4[(size_t)tn * 32 + ks * 8 + 1];
      }
    }
  }
}

// ---------------------------------------------------------------------------
// Head: per WG 64 rows of [T*B, H]; fused GEMM1->tanh->GEMM2->tanh->dot(W3).
// (unchanged, validated r1-r9)
// ---------------------------------------------------------------------------
__device__ __forceinline__ void head_gemm(const _Float16* __restrict__ A,
                                          const _Float16* __restrict__ Wf,
                                          const float* __restrict__ bvec,
                                          _Float16* __restrict__ Yd,
                                          int lane, int w)
{
  const half8* Af = (const half8*)A + w * 512 + lane;
  for (int ct = 0; ct < 16; ++ct) {
    const half8* Bf = (const half8*)Wf + ct * 512 + lane;
    f32x4 acc = {0.f, 0.f, 0.f, 0.f};
    #pragma unroll
    for (int ks = 0; ks < 8; ++ks)
      acc = __builtin_amdgcn_mfma_f32_16x16x32_f16(Af[ks * 64], Bf[ks * 64], acc, 0, 0, 0);
    int col = ct * 16 + (lane & 15);
    float bb = bvec[col];
    int ks2 = col >> 5, kg2 = (col >> 3) & 3, s2 = col & 7;
    #pragma unroll
    for (int r = 0; r < 4; ++r) {
      int row = w * 16 + ((lane >> 4) << 2) + r;
      float v = fast_tanh(acc[r] + bb);
      Yd[(((w * 8 + ks2) * 64) + kg2 * 16 + (row & 15)) * 8 + s2] = (_Float16)v;
    }
  }
}

__global__ void __launch_bounds__(256) head_kernel(
    const _Float16* __restrict__ h_all,
    const _Float16* __restrict__ W1f, const _Float16* __restrict__ W2f,
    const float* __restrict__ b1, const float* __restrict__ b2,
    const float* __restrict__ W3, const float* __restrict__ b3,
    float* __restrict__ out)
{
  __shared__ __align__(16) _Float16 A_s[16384];   // 32 KB
  __shared__ __align__(16) _Float16 Y_s[16384];   // 32 KB
  const int tid = threadIdx.x;
  const size_t r0 = (size_t)blockIdx.x * 64;

  {
    int row = tid >> 2, seg = tid & 3;
    int rtl = row >> 4, lrow = row & 15;
    const half8* hp = (const half8*)(h_all + (r0 + row) * 256 + seg * 64);
    #pragma unroll
    for (int i = 0; i < 8; ++i) {
      int k0 = seg * 64 + i * 8;
      int ks = k0 >> 5, kg = (k0 >> 3) & 3;
      ((half8*)A_s)[(rtl * 8 + ks) * 64 + kg * 16 + lrow] = hp[i];
    }
  }
  __syncthreads();

  const int lane = tid & 63, w = tid >> 6;
  head_gemm(A_s, W1f, b1, Y_s, lane, w);   // y1 = tanh(h @ W1 + b1)
  __syncthreads();
  head_gemm(Y_s, W2f, b2, A_s, lane, w);   // y2 = tanh(y1 @ W2 + b2)
  __syncthreads();

  {
    int row = tid >> 2, part = tid & 3;
    int rtl = row >> 4, lrow = row & 15;
    float p = 0.f;
    #pragma unroll
    for (int kk = 0; kk < 8; ++kk) {
      int k0 = part * 64 + kk * 8;
      int ks = k0 >> 5, kg = (k0 >> 3) & 3;
      half8 y = ((const half8*)A_s)[(rtl * 8 + ks) * 64 + kg * 16 + lrow];
      #pragma unroll
      for (int i = 0; i < 8; ++i) p += (float)y[i] * W3[k0 + i];
    }
    p += __shfl_xor(p, 1);
    p += __shfl_xor(p, 2);
    if (part == 0) {
      size_t r = r0 + row;                 // r = t*256 + b
      int tt = (int)(r >> 8), bb = (int)(r & 255);
      out[(size_t)bb * 512 + tt] = p + b3[0];
    }
  }
}

// ---------------------------------------------------------------------------
extern "C" void kernel_launch(void* const* d_in, const int* in_sizes, int n_in,
                              void* d_out, int out_size, void* d_ws, size_t ws_size,
                              hipStream_t stream)
{
  const float* x  = (const float*)d_in[0];
  const float* Wx = (const float*)d_in[1];
  const float* Wh = (const float*)d_in[2];
  const float* b  = (const float*)d_in[3];
  const float* W1 = (const float*)d_in[4];
  const float* b1 = (const float*)d_in[5];
  const float* W2 = (const float*)d_in[6];
  const float* b2 = (const float*)d_in[7];
  const float* W3 = (const float*)d_in[8];
  const float* b3 = (const float*)d_in[9];
  float* out = (float*)d_out;

  char* ws = (char*)d_ws;
  unsigned*  flags = (unsigned*)ws;                        // 256 u32 (4 KB pad)
  _Float16*  W1f   = (_Float16*)(ws + 4096);               // 128 KB
  _Float16*  W2f   = (_Float16*)(ws + 4096 + 131072);      // 128 KB
  _Float16*  h_all = (_Float16*)(ws + 4096 + 262144);      // [512][256][256] f16 = 64 MB
  if (ws_size < (size_t)4096 + 262144 + 67108864) return;  // insufficient scratch

  hipMemsetAsync(flags, 0, 4096, stream);   // clear flags each replay
  hipLaunchKernelGGL(prep_kernel, dim3(512), dim3(256), 0, stream,
                     W1, W2, W1f, W2f);
  hipLaunchKernelGGL(lstm_rec_kernel, dim3(64), dim3(256), 0, stream,
                     x, Wx, Wh, b, h_all, flags);
  hipLaunchKernelGGL(head_kernel, dim3(2048), dim3(256), 0, stream,
                     h_all, W1f, W2f, b1, b2, W3, b3, out);
}